// Round 1
// baseline (26729.858 us; speedup 1.0000x reference)
//
#include <hip/hip_runtime.h>

// ---------------- problem constants ----------------
#define B_ 8
#define S_ 128
#define H_ 512
#define G_ 2048   // 4H
#define MEL_ 80

// ---------------- ws layout (f32 word offsets) ----------------
#define CTR_WORDS  2048                 // barrier counters (u32)
#define OFF_H0S    2048                 // lstm0 h state [dir][pingpong][b][512] = 16384
#define OFF_C0S    (OFF_H0S + 16384)    // lstm0 c state [dir][b][512] = 8192
#define OFF_H1S    (OFF_C0S + 8192)     // 16384
#define OFF_C1S    (OFF_H1S + 16384)    // 8192
#define OFF_DH     (OFF_C1S + 8192)     // dec h [b][512] = 4096
#define OFF_DC     (OFF_DH + 4096)      // dec c = 4096
#define OFF_DIN    (OFF_DC + 4096)      // din [b][80] (pad to 1024)
#define ZERO_WORDS (OFF_DIN + 1024)     // = 60416 = 236*256
#define OFF_X0     60416                        // [bs][512]   524288
#define OFF_GX0F   (OFF_X0 + 524288)            // [bs][2048] 2097152
#define OFF_GX0B   (OFF_GX0F + 2097152)
#define OFF_H0     (OFF_GX0B + 2097152)         // [bs][1024] 1048576
#define OFF_GX1F   (OFF_H0 + 1048576)
#define OFF_GX1B   (OFF_GX1F + 2097152)
#define OFF_ENC    (OFF_GX1B + 2097152)         // [bs][1024] 1048576
#define OFF_ENCP   (OFF_ENC + 1048576)          // [bs][512]   524288
#define OFF_HW     (OFF_ENCP + 524288)          // [b][512]      4096
#define OFF_SC     (OFF_HW + 4096)              // [b][128]      1024
#define OFF_CTX    (OFF_SC + 1024)              // [b][1024]     8192
#define OFF_HDEC   (OFF_CTX + 8192)             // [b][2048]    16384

// ---------------- helpers ----------------
__device__ __forceinline__ float sigm_f(float x) {
    x = fminf(fmaxf(x, -30.f), 30.f);
    return 1.f / (1.f + __expf(-x));
}
__device__ __forceinline__ float tanh_f(float x) {
    x = fminf(fmaxf(x, -15.f), 15.f);
    float e = __expf(2.f * x);
    return (e - 1.f) / (e + 1.f);
}

// single-use-counter grid barrier (counters zeroed at launch start)
__device__ __forceinline__ void group_barrier(unsigned* c, unsigned nw) {
    __syncthreads();
    if (threadIdx.x == 0) {
        __threadfence();
        __hip_atomic_fetch_add(c, 1u, __ATOMIC_ACQ_REL, __HIP_MEMORY_SCOPE_AGENT);
        while (__hip_atomic_load(c, __ATOMIC_ACQUIRE, __HIP_MEMORY_SCOPE_AGENT) < nw) {
            __builtin_amdgcn_s_sleep(1);
        }
        __threadfence();
    }
    __syncthreads();
}

// ---------------- zero init ----------------
__global__ __launch_bounds__(256) void zero_kernel(float* p) {
    p[blockIdx.x * 256 + threadIdx.x] = 0.f;
}

// ---------------- embedding ----------------
__global__ __launch_bounds__(256) void embed_kernel(const int* __restrict__ text,
                                                    const float* __restrict__ emb,
                                                    float* __restrict__ X) {
    int i = blockIdx.x * 256 + threadIdx.x;   // float4 id, 131072 total
    int bs = i >> 7;
    int h4 = i & 127;
    int ch = text[bs];
    ((float4*)X)[i] = ((const float4*)emb)[ch * 128 + h4];
}

// ---------------- f32 GEMM: C[M,N] = A[M,K] * W[N,K]^T + b1 (+ b2) ----------------
__global__ __launch_bounds__(256) void gemm_f32(const float* __restrict__ A, int lda,
                                                const float* __restrict__ W, int ldw,
                                                const float* __restrict__ b1,
                                                const float* __restrict__ b2,
                                                float* __restrict__ C, int ldc, int K) {
    __shared__ float As[32][68];
    __shared__ float Ws[32][68];
    int tid = threadIdx.x;
    int tx = tid & 15, ty = tid >> 4;
    int n0 = blockIdx.x * 64, m0 = blockIdx.y * 64;
    float acc[4][4] = {};
    int r  = tid >> 3;
    int c4 = (tid & 7) * 4;
    for (int k0 = 0; k0 < K; k0 += 32) {
        float4 a0 = *(const float4*)&A[(m0 + r) * lda + k0 + c4];
        float4 a1 = *(const float4*)&A[(m0 + r + 32) * lda + k0 + c4];
        float4 w0 = *(const float4*)&W[(n0 + r) * ldw + k0 + c4];
        float4 w1 = *(const float4*)&W[(n0 + r + 32) * ldw + k0 + c4];
        As[c4 + 0][r] = a0.x; As[c4 + 1][r] = a0.y; As[c4 + 2][r] = a0.z; As[c4 + 3][r] = a0.w;
        As[c4 + 0][r + 32] = a1.x; As[c4 + 1][r + 32] = a1.y; As[c4 + 2][r + 32] = a1.z; As[c4 + 3][r + 32] = a1.w;
        Ws[c4 + 0][r] = w0.x; Ws[c4 + 1][r] = w0.y; Ws[c4 + 2][r] = w0.z; Ws[c4 + 3][r] = w0.w;
        Ws[c4 + 0][r + 32] = w1.x; Ws[c4 + 1][r + 32] = w1.y; Ws[c4 + 2][r + 32] = w1.z; Ws[c4 + 3][r + 32] = w1.w;
        __syncthreads();
#pragma unroll 8
        for (int kk = 0; kk < 32; ++kk) {
            float4 av = *(const float4*)&As[kk][ty * 4];
            float4 wv = *(const float4*)&Ws[kk][tx * 4];
            acc[0][0] = fmaf(av.x, wv.x, acc[0][0]); acc[0][1] = fmaf(av.x, wv.y, acc[0][1]);
            acc[0][2] = fmaf(av.x, wv.z, acc[0][2]); acc[0][3] = fmaf(av.x, wv.w, acc[0][3]);
            acc[1][0] = fmaf(av.y, wv.x, acc[1][0]); acc[1][1] = fmaf(av.y, wv.y, acc[1][1]);
            acc[1][2] = fmaf(av.y, wv.z, acc[1][2]); acc[1][3] = fmaf(av.y, wv.w, acc[1][3]);
            acc[2][0] = fmaf(av.z, wv.x, acc[2][0]); acc[2][1] = fmaf(av.z, wv.y, acc[2][1]);
            acc[2][2] = fmaf(av.z, wv.z, acc[2][2]); acc[2][3] = fmaf(av.z, wv.w, acc[2][3]);
            acc[3][0] = fmaf(av.w, wv.x, acc[3][0]); acc[3][1] = fmaf(av.w, wv.y, acc[3][1]);
            acc[3][2] = fmaf(av.w, wv.z, acc[3][2]); acc[3][3] = fmaf(av.w, wv.w, acc[3][3]);
        }
        __syncthreads();
    }
#pragma unroll
    for (int i = 0; i < 4; ++i)
#pragma unroll
        for (int j = 0; j < 4; ++j) {
            int n = n0 + tx * 4 + j;
            int m = m0 + ty * 4 + i;
            float bias = b1[n] + (b2 ? b2[n] : 0.f);
            C[m * ldc + n] = acc[i][j] + bias;
        }
}

// ---------------- persistent bidirectional LSTM layer ----------------
// grid 128 WGs: dir = wg>>6 (64 WGs each), slot = wg&63 owns j in [slot*8, slot*8+8)
__global__ __launch_bounds__(256) void lstm_kernel(const float* __restrict__ GXf,
                                                   const float* __restrict__ GXb,
                                                   const float* __restrict__ Whh_f,
                                                   const float* __restrict__ Whh_b,
                                                   float* __restrict__ Hout,
                                                   float* __restrict__ hstate,
                                                   float* __restrict__ cstate,
                                                   unsigned* __restrict__ ctrs) {
    int wg = blockIdx.x;
    int dir = wg >> 6;
    int slot = wg & 63;
    const float* GX  = dir ? GXb : GXf;
    const float* Whh = dir ? Whh_b : Whh_f;
    float* hs0 = hstate + dir * 8192;   // [pingpong][b][512]
    float* cs  = cstate + dir * 4096;   // [b][512]
    unsigned* ctr = ctrs + dir * 128;

    int tid = threadIdx.x;
    int q  = tid >> 6;
    int jj = (tid >> 3) & 7;
    int bb = tid & 7;
    int j   = slot * 8 + jj;
    int row = q * 512 + j;
    const float* wr = Whh + row * 512;

    __shared__ float hsh[8][516];
    __shared__ float gsh[4][8][8];

    for (int t = 0; t < 128; ++t) {
        int st = dir ? (127 - t) : t;
        const float* hsr = hs0 + (t & 1) * 4096;
        float* hsw = hs0 + ((t & 1) ^ 1) * 4096;
        // stage h into LDS (padded stride 516 -> conflict-free b-spread)
#pragma unroll
        for (int u = 0; u < 4; ++u) {
            int n = tid + u * 256;           // 0..1023 float4s
            int b2 = n >> 7, k4 = n & 127;
            float4 hv = *(const float4*)&hsr[b2 * 512 + k4 * 4];
            *(float4*)&hsh[b2][k4 * 4] = hv;
        }
        __syncthreads();

        float acc = GX[(bb * S_ + st) * G_ + row];
        float a0 = 0.f, a1 = 0.f, a2 = 0.f, a3 = 0.f;
#pragma unroll 8
        for (int k = 0; k < 512; k += 4) {
            float4 wv = *(const float4*)(wr + k);
            float4 hv = *(const float4*)&hsh[bb][k];
            a0 = fmaf(wv.x, hv.x, a0);
            a1 = fmaf(wv.y, hv.y, a1);
            a2 = fmaf(wv.z, hv.z, a2);
            a3 = fmaf(wv.w, hv.w, a3);
        }
        acc += (a0 + a1) + (a2 + a3);
        gsh[q][jj][bb] = acc;
        __syncthreads();

        if (q == 0) {
            float gi = gsh[0][jj][bb], gf = gsh[1][jj][bb];
            float gg = gsh[2][jj][bb], go = gsh[3][jj][bb];
            float c  = cs[bb * 512 + j];
            float c2 = sigm_f(gf) * c + sigm_f(gi) * tanh_f(gg);
            float h2 = sigm_f(go) * tanh_f(c2);
            cs[bb * 512 + j] = c2;
            hsw[bb * 512 + j] = h2;
            Hout[(bb * S_ + st) * 1024 + dir * 512 + j] = h2;
        }
        group_barrier(ctr + t, 64);
    }
}

// ---------------- persistent attention decoder, 64 WGs ----------------
__global__ __launch_bounds__(256) void decoder_kernel(float* __restrict__ ws,
                                                      const float* __restrict__ attn_W,
                                                      const float* __restrict__ attn_v,
                                                      const float* __restrict__ dec_Wih,
                                                      const float* __restrict__ dec_Whh,
                                                      const float* __restrict__ dec_bih,
                                                      const float* __restrict__ dec_bhh,
                                                      const float* __restrict__ mel_W,
                                                      const float* __restrict__ mel_b,
                                                      float* __restrict__ out, int T,
                                                      unsigned* __restrict__ ctrs) {
    float* ENC  = ws + OFF_ENC;
    float* ENCP = ws + OFF_ENCP;
    float* DH   = ws + OFF_DH;
    float* DC   = ws + OFF_DC;
    float* DIN  = ws + OFF_DIN;
    float* HW   = ws + OFF_HW;
    float* SC   = ws + OFF_SC;
    float* CTX  = ws + OFF_CTX;
    float* HDEC = ws + OFF_HDEC;

    int wg = blockIdx.x;     // 0..63
    int tid = threadIdx.x;

    __shared__ float att[128];
    __shared__ float tmp[128];
    __shared__ float gsh[4][8][8];

    for (int t = 0; t < T; ++t) {
        // ---- stage A: hW = h @ W_h^T ; mel_{t-1} = h @ mel_W^T + mel_b ----
        if (wg < 16) {
            int id = wg * 256 + tid;
            int hr = id >> 3, bb = id & 7;
            const float* wrow = attn_W + hr * 1536;
            const float* hp = DH + bb * 512;
            float a0 = 0.f, a1 = 0.f, a2 = 0.f, a3 = 0.f;
#pragma unroll 8
            for (int k = 0; k < 512; k += 4) {
                float4 wv = *(const float4*)(wrow + k);
                float4 hv = *(const float4*)(hp + k);
                a0 = fmaf(wv.x, hv.x, a0); a1 = fmaf(wv.y, hv.y, a1);
                a2 = fmaf(wv.z, hv.z, a2); a3 = fmaf(wv.w, hv.w, a3);
            }
            HW[bb * 512 + hr] = (a0 + a1) + (a2 + a3);
        } else if (wg < 19 && t > 0) {
            int id = (wg - 16) * 256 + tid;
            if (id < 640) {
                int mr = id >> 3, bb = id & 7;
                const float* wrow = mel_W + mr * 512;
                const float* hp = DH + bb * 512;
                float a0 = 0.f, a1 = 0.f, a2 = 0.f, a3 = 0.f;
#pragma unroll 8
                for (int k = 0; k < 512; k += 4) {
                    float4 wv = *(const float4*)(wrow + k);
                    float4 hv = *(const float4*)(hp + k);
                    a0 = fmaf(wv.x, hv.x, a0); a1 = fmaf(wv.y, hv.y, a1);
                    a2 = fmaf(wv.z, hv.z, a2); a3 = fmaf(wv.w, hv.w, a3);
                }
                float mel = (a0 + a1) + (a2 + a3) + mel_b[mr];
                DIN[bb * 80 + mr] = mel;
                out[bb * MEL_ * T + mr * T + (t - 1)] = mel;
            }
        }
        group_barrier(ctrs + t * 4 + 0, 64);

        // ---- stage B: scores (WG 0..31) | hdec rows 0..1023 (WG 32..63) ----
        if (wg < 32) {
            int r = wg * 32 + (tid >> 3);
            int bb = r >> 7, s = r & 127;
            int ks = (tid & 7) * 64;
            const float* ep = ENCP + (bb * S_ + s) * 512;
            const float* hw = HW + bb * 512;
            float acc = 0.f;
#pragma unroll 4
            for (int k = ks; k < ks + 64; ++k) {
                float e = ep[k] + hw[k];
                acc = fmaf(tanh_f(e), attn_v[k], acc);
            }
            acc += __shfl_xor(acc, 1);
            acc += __shfl_xor(acc, 2);
            acc += __shfl_xor(acc, 4);
            if ((tid & 7) == 0) SC[bb * 128 + s] = acc;
        } else {
            int id = (wg - 32) * 256 + tid;
            int row = id >> 3, bb = id & 7;
            const float* wrow = dec_Whh + row * 512;
            const float* hp = DH + bb * 512;
            float a0 = dec_bih[row] + dec_bhh[row], a1 = 0.f, a2 = 0.f, a3 = 0.f;
#pragma unroll 8
            for (int k = 0; k < 512; k += 4) {
                float4 wv = *(const float4*)(wrow + k);
                float4 hv = *(const float4*)(hp + k);
                a0 = fmaf(wv.x, hv.x, a0); a1 = fmaf(wv.y, hv.y, a1);
                a2 = fmaf(wv.z, hv.z, a2); a3 = fmaf(wv.w, hv.w, a3);
            }
            HDEC[bb * G_ + row] = (a0 + a1) + (a2 + a3);
        }
        group_barrier(ctrs + t * 4 + 1, 64);

        // ---- stage C: softmax+ctx (WG 0..31) | hdec rows 1024..2047 ----
        if (wg < 32) {
            int bb = wg >> 2;
            int d = (wg & 3) * 256 + tid;
            float sv = (tid < 128) ? SC[bb * 128 + tid] : -3e38f;
            if (tid < 128) tmp[tid] = sv;
            __syncthreads();
            for (int off = 64; off >= 1; off >>= 1) {
                if (tid < off) tmp[tid] = fmaxf(tmp[tid], tmp[tid + off]);
                __syncthreads();
            }
            float mx = tmp[0];
            __syncthreads();
            if (tid < 128) att[tid] = __expf(sv - mx);
            __syncthreads();
            if (tid < 64) tmp[tid] = att[tid] + att[tid + 64];
            __syncthreads();
            for (int off = 32; off >= 1; off >>= 1) {
                if (tid < off) tmp[tid] += tmp[tid + off];
                __syncthreads();
            }
            float inv = 1.f / tmp[0];
            const float* ebase = ENC + bb * S_ * 1024 + d;
            float acc = 0.f;
#pragma unroll 4
            for (int s = 0; s < 128; ++s) {
                acc = fmaf(att[s], ebase[s * 1024], acc);
            }
            CTX[bb * 1024 + d] = acc * inv;
        } else {
            int id = (wg - 32) * 256 + tid;
            int row = 1024 + (id >> 3);
            int bb = id & 7;
            const float* wrow = dec_Whh + row * 512;
            const float* hp = DH + bb * 512;
            float a0 = dec_bih[row] + dec_bhh[row], a1 = 0.f, a2 = 0.f, a3 = 0.f;
#pragma unroll 8
            for (int k = 0; k < 512; k += 4) {
                float4 wv = *(const float4*)(wrow + k);
                float4 hv = *(const float4*)(hp + k);
                a0 = fmaf(wv.x, hv.x, a0); a1 = fmaf(wv.y, hv.y, a1);
                a2 = fmaf(wv.z, hv.z, a2); a3 = fmaf(wv.w, hv.w, a3);
            }
            HDEC[bb * G_ + row] = (a0 + a1) + (a2 + a3);
        }
        group_barrier(ctrs + t * 4 + 2, 64);

        // ---- stage D: gates (K=1104) + fused cell; WG wg owns j in [wg*8, wg*8+8) ----
        {
            int q  = tid >> 6;
            int jj = (tid >> 3) & 7;
            int bb = tid & 7;
            int j   = wg * 8 + jj;
            int row = q * 512 + j;
            const float* wrow = dec_Wih + row * 1104;
            float acc = HDEC[bb * G_ + row];
            float a0 = 0.f, a1 = 0.f, a2 = 0.f, a3 = 0.f;
#pragma unroll
            for (int k = 0; k < 80; k += 4) {
                float4 wv = *(const float4*)(wrow + k);
                float4 xv = *(const float4*)&DIN[bb * 80 + k];
                a0 = fmaf(wv.x, xv.x, a0); a1 = fmaf(wv.y, xv.y, a1);
                a2 = fmaf(wv.z, xv.z, a2); a3 = fmaf(wv.w, xv.w, a3);
            }
#pragma unroll 8
            for (int k = 0; k < 1024; k += 4) {
                float4 wv = *(const float4*)(wrow + 80 + k);
                float4 xv = *(const float4*)&CTX[bb * 1024 + k];
                a0 = fmaf(wv.x, xv.x, a0); a1 = fmaf(wv.y, xv.y, a1);
                a2 = fmaf(wv.z, xv.z, a2); a3 = fmaf(wv.w, xv.w, a3);
            }
            acc += (a0 + a1) + (a2 + a3);
            gsh[q][jj][bb] = acc;
            __syncthreads();
            if (q == 0) {
                float gi = gsh[0][jj][bb], gf = gsh[1][jj][bb];
                float gg = gsh[2][jj][bb], go = gsh[3][jj][bb];
                float c  = DC[bb * 512 + j];
                float c2 = sigm_f(gf) * c + sigm_f(gi) * tanh_f(gg);
                float h2 = sigm_f(go) * tanh_f(c2);
                DC[bb * 512 + j] = c2;
                DH[bb * 512 + j] = h2;
            }
        }
        group_barrier(ctrs + t * 4 + 3, 64);
    }

    // ---- final mel (t = T-1) ----
    if (wg < 3) {
        int id = wg * 256 + tid;
        if (id < 640) {
            int mr = id >> 3, bb = id & 7;
            const float* wrow = mel_W + mr * 512;
            const float* hp = DH + bb * 512;
            float a0 = 0.f, a1 = 0.f, a2 = 0.f, a3 = 0.f;
#pragma unroll 8
            for (int k = 0; k < 512; k += 4) {
                float4 wv = *(const float4*)(wrow + k);
                float4 hv = *(const float4*)(hp + k);
                a0 = fmaf(wv.x, hv.x, a0); a1 = fmaf(wv.y, hv.y, a1);
                a2 = fmaf(wv.z, hv.z, a2); a3 = fmaf(wv.w, hv.w, a3);
            }
            out[bb * MEL_ * T + mr * T + (T - 1)] = (a0 + a1) + (a2 + a3) + mel_b[mr];
        }
    }
}

// ---------------- host launch ----------------
extern "C" void kernel_launch(void* const* d_in, const int* in_sizes, int n_in,
                              void* d_out, int out_size, void* d_ws, size_t ws_size,
                              hipStream_t stream) {
    const int*   text  = (const int*)d_in[0];
    const float* emb   = (const float*)d_in[2];
    const float* Wih00 = (const float*)d_in[3];
    const float* Whh00 = (const float*)d_in[4];
    const float* bih00 = (const float*)d_in[5];
    const float* bhh00 = (const float*)d_in[6];
    const float* Wih01 = (const float*)d_in[7];
    const float* Whh01 = (const float*)d_in[8];
    const float* bih01 = (const float*)d_in[9];
    const float* bhh01 = (const float*)d_in[10];
    const float* Wih10 = (const float*)d_in[11];
    const float* Whh10 = (const float*)d_in[12];
    const float* bih10 = (const float*)d_in[13];
    const float* bhh10 = (const float*)d_in[14];
    const float* Wih11 = (const float*)d_in[15];
    const float* Whh11 = (const float*)d_in[16];
    const float* bih11 = (const float*)d_in[17];
    const float* bhh11 = (const float*)d_in[18];
    const float* attn_W = (const float*)d_in[19];
    const float* attn_b = (const float*)d_in[20];
    const float* attn_v = (const float*)d_in[21];
    const float* dec_Wih = (const float*)d_in[22];
    const float* dec_Whh = (const float*)d_in[23];
    const float* dec_bih = (const float*)d_in[24];
    const float* dec_bhh = (const float*)d_in[25];
    const float* mel_W = (const float*)d_in[26];
    const float* mel_b = (const float*)d_in[27];

    float* ws = (float*)d_ws;
    unsigned* ctrs = (unsigned*)d_ws;
    float* out = (float*)d_out;
    int T = out_size / (B_ * MEL_);   // 200

    // zero barrier counters + recurrent states
    zero_kernel<<<ZERO_WORDS / 256, 256, 0, stream>>>(ws);

    // embedding
    embed_kernel<<<512, 256, 0, stream>>>(text, emb, ws + OFF_X0);

    // layer0 input projections (bias folded: bih + bhh)
    gemm_f32<<<dim3(32, 16), 256, 0, stream>>>(ws + OFF_X0, 512, Wih00, 512,
                                               bih00, bhh00, ws + OFF_GX0F, 2048, 512);
    gemm_f32<<<dim3(32, 16), 256, 0, stream>>>(ws + OFF_X0, 512, Wih01, 512,
                                               bih01, bhh01, ws + OFF_GX0B, 2048, 512);
    // layer0 recurrence
    lstm_kernel<<<128, 256, 0, stream>>>(ws + OFF_GX0F, ws + OFF_GX0B, Whh00, Whh01,
                                         ws + OFF_H0, ws + OFF_H0S, ws + OFF_C0S, ctrs);
    // layer1 input projections
    gemm_f32<<<dim3(32, 16), 256, 0, stream>>>(ws + OFF_H0, 1024, Wih10, 1024,
                                               bih10, bhh10, ws + OFF_GX1F, 2048, 1024);
    gemm_f32<<<dim3(32, 16), 256, 0, stream>>>(ws + OFF_H0, 1024, Wih11, 1024,
                                               bih11, bhh11, ws + OFF_GX1B, 2048, 1024);
    // layer1 recurrence -> enc
    lstm_kernel<<<128, 256, 0, stream>>>(ws + OFF_GX1F, ws + OFF_GX1B, Whh10, Whh11,
                                         ws + OFF_ENC, ws + OFF_H1S, ws + OFF_C1S, ctrs + 256);
    // enc_part = enc @ W_e^T + attn_b   (W_e = attn_W[:, 512:], row stride 1536)
    gemm_f32<<<dim3(8, 16), 256, 0, stream>>>(ws + OFF_ENC, 1024, attn_W + 512, 1536,
                                              attn_b, nullptr, ws + OFF_ENCP, 512, 1024);
    // decoder
    decoder_kernel<<<64, 256, 0, stream>>>(ws, attn_W, attn_v, dec_Wih, dec_Whh,
                                           dec_bih, dec_bhh, mel_W, mel_b, out, T,
                                           ctrs + 512);
}

// Round 3
// 17171.414 us; speedup vs baseline: 1.5566x; 1.5566x over previous
//
#include <hip/hip_runtime.h>

// ---------------- problem constants ----------------
#define B_ 8
#define S_ 128
#define H_ 512
#define G_ 2048   // 4H
#define MEL_ 80

// ---------------- ws layout (32-bit word offsets) ----------------
// flag groups: each group 1024 words (64 flags x 16-word stride = own 64B line)
#define FLG_DEC    0
#define FLG_L0     1024     // lstm0: dir0 @ +0, dir1 @ +1024
#define FLG_L1     3072     // lstm1: dir0 @ +0, dir1 @ +1024
#define OFF_H0S    8192                 // lstm0 h [dir][pingpong][b][512] = 16384
#define OFF_H1S    (OFF_H0S + 16384)    // 16384
#define OFF_DH     (OFF_H1S + 16384)    // dec h [b][512] = 4096
#define OFF_DIN    (OFF_DH + 4096)      // din [b][128] = 1024 (80 used/row)
#define OFF_HW     (OFF_DIN + 1024)     // [b][512] = 4096
#define OFF_CTX    (OFF_HW + 4096)      // [b][1024] = 8192
#define ZERO_WORDS (OFF_CTX + 8192)     // = 58368 = 228*256
#define OFF_X0     58368                        // [bs][512]   524288
#define OFF_GX0F   (OFF_X0 + 524288)            // [bs][2048] 2097152
#define OFF_GX0B   (OFF_GX0F + 2097152)
#define OFF_H0     (OFF_GX0B + 2097152)         // [bs][1024] 1048576
#define OFF_GX1F   (OFF_H0 + 1048576)
#define OFF_GX1B   (OFF_GX1F + 2097152)
#define OFF_ENC    (OFF_GX1B + 2097152)         // [bs][1024] 1048576
#define OFF_ENCP   (OFF_ENC + 1048576)          // [bs][512]   524288

// ---------------- helpers ----------------
__device__ __forceinline__ float sigm_f(float x) {
    x = fminf(fmaxf(x, -30.f), 30.f);
    return 1.f / (1.f + __expf(-x));
}
__device__ __forceinline__ float tanh_f(float x) {
    x = fminf(fmaxf(x, -15.f), 15.f);
    float e = __expf(2.f * x);
    return (e - 1.f) / (e + 1.f);
}

// system-scope (LLC-coherent, cache-bypassing) scalar access for cross-WG state
__device__ __forceinline__ void sysw_u(unsigned* p, unsigned v) {
    __hip_atomic_store(p, v, __ATOMIC_RELAXED, __HIP_MEMORY_SCOPE_SYSTEM);
}
__device__ __forceinline__ unsigned sysr_u(const unsigned* p) {
    return __hip_atomic_load(p, __ATOMIC_RELAXED, __HIP_MEMORY_SCOPE_SYSTEM);
}
__device__ __forceinline__ void sysw_f(float* p, float v) {
    sysw_u((unsigned*)p, __float_as_uint(v));
}
__device__ __forceinline__ float sysr_f(const float* p) {
    return __uint_as_float(sysr_u((const unsigned*)p));
}

// flag-array grid barrier for a 64-WG group.
// - arrival: explicit vmcnt drain (our cross-WG data stores are system-scope,
//   so vmcnt(0) == "data at LLC"), then one store to the WG's own cacheline
// - wait: wave 0's 64 lanes each poll ONE peer flag, RELAXED system-scope
//   loads -> no per-iteration cache invalidates, local L2 stays warm.
__device__ __forceinline__ void flag_barrier(unsigned* flags, int wg, unsigned phase) {
    asm volatile("s_waitcnt vmcnt(0) lgkmcnt(0)" ::: "memory");
    __syncthreads();
    if (threadIdx.x == 0)
        sysw_u(flags + wg * 16, phase);
    if (threadIdx.x < 64) {
        while (sysr_u(flags + threadIdx.x * 16) < phase)
            __builtin_amdgcn_s_sleep(2);
    }
    asm volatile("s_waitcnt vmcnt(0)" ::: "memory");
    __syncthreads();
}

// ---------------- zero init ----------------
__global__ __launch_bounds__(256) void zero_kernel(float* p) {
    p[blockIdx.x * 256 + threadIdx.x] = 0.f;
}

// ---------------- embedding ----------------
__global__ __launch_bounds__(256) void embed_kernel(const int* __restrict__ text,
                                                    const float* __restrict__ emb,
                                                    float* __restrict__ X) {
    int i = blockIdx.x * 256 + threadIdx.x;   // float4 id, 131072 total
    int bs = i >> 7;
    int h4 = i & 127;
    int ch = text[bs];
    ((float4*)X)[i] = ((const float4*)emb)[ch * 128 + h4];
}

// ---------------- f32 GEMM: C[M,N] = A[M,K] * W[N,K]^T + b1 (+ b2) ----------------
__global__ __launch_bounds__(256) void gemm_f32(const float* __restrict__ A, int lda,
                                                const float* __restrict__ W, int ldw,
                                                const float* __restrict__ b1,
                                                const float* __restrict__ b2,
                                                float* __restrict__ C, int ldc, int K) {
    __shared__ float As[32][68];
    __shared__ float Ws[32][68];
    int tid = threadIdx.x;
    int tx = tid & 15, ty = tid >> 4;
    int n0 = blockIdx.x * 64, m0 = blockIdx.y * 64;
    float acc[4][4] = {};
    int r  = tid >> 3;
    int c4 = (tid & 7) * 4;
    for (int k0 = 0; k0 < K; k0 += 32) {
        float4 a0 = *(const float4*)&A[(m0 + r) * lda + k0 + c4];
        float4 a1 = *(const float4*)&A[(m0 + r + 32) * lda + k0 + c4];
        float4 w0 = *(const float4*)&W[(n0 + r) * ldw + k0 + c4];
        float4 w1 = *(const float4*)&W[(n0 + r + 32) * ldw + k0 + c4];
        As[c4 + 0][r] = a0.x; As[c4 + 1][r] = a0.y; As[c4 + 2][r] = a0.z; As[c4 + 3][r] = a0.w;
        As[c4 + 0][r + 32] = a1.x; As[c4 + 1][r + 32] = a1.y; As[c4 + 2][r + 32] = a1.z; As[c4 + 3][r + 32] = a1.w;
        Ws[c4 + 0][r] = w0.x; Ws[c4 + 1][r] = w0.y; Ws[c4 + 2][r] = w0.z; Ws[c4 + 3][r] = w0.w;
        Ws[c4 + 0][r + 32] = w1.x; Ws[c4 + 1][r + 32] = w1.y; Ws[c4 + 2][r + 32] = w1.z; Ws[c4 + 3][r + 32] = w1.w;
        __syncthreads();
#pragma unroll 8
        for (int kk = 0; kk < 32; ++kk) {
            float4 av = *(const float4*)&As[kk][ty * 4];
            float4 wv = *(const float4*)&Ws[kk][tx * 4];
            acc[0][0] = fmaf(av.x, wv.x, acc[0][0]); acc[0][1] = fmaf(av.x, wv.y, acc[0][1]);
            acc[0][2] = fmaf(av.x, wv.z, acc[0][2]); acc[0][3] = fmaf(av.x, wv.w, acc[0][3]);
            acc[1][0] = fmaf(av.y, wv.x, acc[1][0]); acc[1][1] = fmaf(av.y, wv.y, acc[1][1]);
            acc[1][2] = fmaf(av.y, wv.z, acc[1][2]); acc[1][3] = fmaf(av.y, wv.w, acc[1][3]);
            acc[2][0] = fmaf(av.z, wv.x, acc[2][0]); acc[2][1] = fmaf(av.z, wv.y, acc[2][1]);
            acc[2][2] = fmaf(av.z, wv.z, acc[2][2]); acc[2][3] = fmaf(av.z, wv.w, acc[2][3]);
            acc[3][0] = fmaf(av.w, wv.x, acc[3][0]); acc[3][1] = fmaf(av.w, wv.y, acc[3][1]);
            acc[3][2] = fmaf(av.w, wv.z, acc[3][2]); acc[3][3] = fmaf(av.w, wv.w, acc[3][3]);
        }
        __syncthreads();
    }
#pragma unroll
    for (int i = 0; i < 4; ++i)
#pragma unroll
        for (int j = 0; j < 4; ++j) {
            int n = n0 + tx * 4 + j;
            int m = m0 + ty * 4 + i;
            float bias = b1[n] + (b2 ? b2[n] : 0.f);
            C[m * ldc + n] = acc[i][j] + bias;
        }
}

// ---------------- persistent bidirectional LSTM layer ----------------
// grid 128 WGs: dir = wg>>6 (independent 64-WG barrier groups), slot = wg&63
__global__ __launch_bounds__(256) void lstm_kernel(const float* __restrict__ GXf,
                                                   const float* __restrict__ GXb,
                                                   const float* __restrict__ Whh_f,
                                                   const float* __restrict__ Whh_b,
                                                   float* __restrict__ Hout,
                                                   float* __restrict__ hstate,
                                                   unsigned* __restrict__ flagsL) {
    int wg = blockIdx.x;
    int dir = wg >> 6;
    int slot = wg & 63;
    const float* GX  = dir ? GXb : GXf;
    const float* Whh = dir ? Whh_b : Whh_f;
    float* hs0 = hstate + dir * 8192;   // [pingpong][b][512]
    unsigned* flags = flagsL + dir * 1024;

    int tid = threadIdx.x;
    int q  = tid >> 6;
    int jj = (tid >> 3) & 7;
    int bb = tid & 7;
    int j   = slot * 8 + jj;
    int row = q * 512 + j;
    const float* wr = Whh + row * 512;

    __shared__ float hsh[8][516];
    __shared__ float gsh[4][8][8];

    float c_reg = 0.f;   // cell state lives in registers of the q==0 threads

    for (int t = 0; t < 128; ++t) {
        int st = dir ? (127 - t) : t;
        const float* hsr = hs0 + (t & 1) * 4096;
        float* hsw = hs0 + ((t & 1) ^ 1) * 4096;
        // stage h into LDS (system loads: h written by other WGs at LLC)
#pragma unroll
        for (int u = 0; u < 16; ++u) {
            int n = tid + u * 256;           // 0..4095
            int b2 = n >> 9, k = n & 511;
            hsh[b2][k] = sysr_f(hsr + b2 * 512 + k);
        }
        __syncthreads();

        float acc = GX[(bb * S_ + st) * G_ + row];
        float a0 = 0.f, a1 = 0.f, a2 = 0.f, a3 = 0.f;
#pragma unroll 8
        for (int k = 0; k < 512; k += 4) {
            float4 wv = *(const float4*)(wr + k);
            float4 hv = *(const float4*)&hsh[bb][k];
            a0 = fmaf(wv.x, hv.x, a0);
            a1 = fmaf(wv.y, hv.y, a1);
            a2 = fmaf(wv.z, hv.z, a2);
            a3 = fmaf(wv.w, hv.w, a3);
        }
        acc += (a0 + a1) + (a2 + a3);
        gsh[q][jj][bb] = acc;
        __syncthreads();

        if (q == 0) {
            float gi = gsh[0][jj][bb], gf = gsh[1][jj][bb];
            float gg = gsh[2][jj][bb], go = gsh[3][jj][bb];
            float c2 = sigm_f(gf) * c_reg + sigm_f(gi) * tanh_f(gg);
            float h2 = sigm_f(go) * tanh_f(c2);
            c_reg = c2;
            sysw_f(hsw + bb * 512 + j, h2);
            Hout[(bb * S_ + st) * 1024 + dir * 512 + j] = h2;
        }
        flag_barrier(flags, slot, (unsigned)(t + 1));
    }
}

// ---------------- persistent attention decoder, 64 WGs, 3 barriers/step ----------------
union DecSMem {
    struct { float dh[8][516]; } p0;
    struct { float hw[516]; float tmp[2][128]; float att[128]; float red[128]; } p1;
    struct { float ctx[8][1028]; float din[8][132]; float gsh[4][8][8]; } p2;
};

__global__ __launch_bounds__(256) void decoder_kernel(float* __restrict__ ws,
                                                      const float* __restrict__ attn_W,
                                                      const float* __restrict__ attn_v,
                                                      const float* __restrict__ dec_Wih,
                                                      const float* __restrict__ dec_Whh,
                                                      const float* __restrict__ dec_bih,
                                                      const float* __restrict__ dec_bhh,
                                                      const float* __restrict__ mel_W,
                                                      const float* __restrict__ mel_b,
                                                      float* __restrict__ out, int T,
                                                      unsigned* __restrict__ flags) {
    float* ENC  = ws + OFF_ENC;
    float* ENCP = ws + OFF_ENCP;
    float* DH   = ws + OFF_DH;
    float* DIN  = ws + OFF_DIN;
    float* HW   = ws + OFF_HW;
    float* CTX  = ws + OFF_CTX;

    int wg = blockIdx.x;     // 0..63
    int tid = threadIdx.x;

    __shared__ DecSMem sm;

    // P0/P2 row ownership (same mapping both phases; hdec result stays in reg)
    int q  = tid >> 6;
    int jj = (tid >> 3) & 7;
    int bb = tid & 7;
    int j   = wg * 8 + jj;
    int row = q * 512 + j;
    const float* whh_row = dec_Whh + row * 512;
    const float* wih_row = dec_Wih + row * 1104;
    float bias_row = dec_bih[row] + dec_bhh[row];

    // P1 attention mapping: 8 WGs per batch
    int ab  = wg >> 3;       // batch
    int oct = wg & 7;        // d-slice [oct*128, +128)

    float c_reg = 0.f;       // decoder cell state (q==0 threads)

    for (int t = 0; t < T; ++t) {
        // ================= P0: hW | mel_{t-1} | hdec(->reg) =================
        // stage DH into LDS (system loads)
#pragma unroll
        for (int u = 0; u < 16; ++u) {
            int n = tid + u * 256;
            int b2 = n >> 9, k = n & 511;
            sm.p0.dh[b2][k] = sysr_f(DH + b2 * 512 + k);
        }
        __syncthreads();

        // hdec: every thread, own (row, bb), result kept in register
        float hdec_acc;
        {
            float a0 = bias_row, a1 = 0.f, a2 = 0.f, a3 = 0.f;
#pragma unroll 8
            for (int k = 0; k < 512; k += 4) {
                float4 wv = *(const float4*)(whh_row + k);
                float4 hv = *(const float4*)&sm.p0.dh[bb][k];
                a0 = fmaf(wv.x, hv.x, a0); a1 = fmaf(wv.y, hv.y, a1);
                a2 = fmaf(wv.z, hv.z, a2); a3 = fmaf(wv.w, hv.w, a3);
            }
            hdec_acc = (a0 + a1) + (a2 + a3);
        }

        if (wg < 16) {
            // hW: 4096 dots over WGs 0..15
            int id = wg * 256 + tid;
            int hr = id >> 3, b2 = id & 7;
            const float* wrow = attn_W + hr * 1536;   // W_h = attn_W[:, :512]
            float a0 = 0.f, a1 = 0.f, a2 = 0.f, a3 = 0.f;
#pragma unroll 8
            for (int k = 0; k < 512; k += 4) {
                float4 wv = *(const float4*)(wrow + k);
                float4 hv = *(const float4*)&sm.p0.dh[b2][k];
                a0 = fmaf(wv.x, hv.x, a0); a1 = fmaf(wv.y, hv.y, a1);
                a2 = fmaf(wv.z, hv.z, a2); a3 = fmaf(wv.w, hv.w, a3);
            }
            sysw_f(HW + b2 * 512 + hr, (a0 + a1) + (a2 + a3));
        } else if (wg < 19 && t > 0) {
            // mel from h_{t-1}: 640 dots over WGs 16..18
            int id = (wg - 16) * 256 + tid;
            if (id < 640) {
                int mr = id >> 3, b2 = id & 7;
                const float* wrow = mel_W + mr * 512;
                float a0 = 0.f, a1 = 0.f, a2 = 0.f, a3 = 0.f;
#pragma unroll 8
                for (int k = 0; k < 512; k += 4) {
                    float4 wv = *(const float4*)(wrow + k);
                    float4 hv = *(const float4*)&sm.p0.dh[b2][k];
                    a0 = fmaf(wv.x, hv.x, a0); a1 = fmaf(wv.y, hv.y, a1);
                    a2 = fmaf(wv.z, hv.z, a2); a3 = fmaf(wv.w, hv.w, a3);
                }
                float mel = (a0 + a1) + (a2 + a3) + mel_b[mr];
                sysw_f(DIN + b2 * 128 + mr, mel);
                out[b2 * MEL_ * T + mr * T + (t - 1)] = mel;
            }
        }
        flag_barrier(flags, wg, (unsigned)(3 * t + 1));

        // ================= P1: scores + softmax + ctx slice (all 64 WGs) =================
        float inv;
        {
            // stage HW[ab] into LDS
            for (int n = tid; n < 512; n += 256)
                sm.p1.hw[n] = sysr_f(HW + ab * 512 + n);
            __syncthreads();

            // scores: s = tid&127, k-half = tid>>7
            int s  = tid & 127;
            int kh = tid >> 7;
            const float* ep = ENCP + (ab * S_ + s) * 512 + kh * 256;
            const float* hw = sm.p1.hw + kh * 256;
            const float* vv = attn_v + kh * 256;
            float a0 = 0.f, a1 = 0.f, a2 = 0.f, a3 = 0.f;
#pragma unroll 4
            for (int k = 0; k < 256; k += 4) {
                float4 e4 = *(const float4*)(ep + k);
                float4 h4 = *(const float4*)(hw + k);
                float4 v4 = *(const float4*)(vv + k);
                a0 = fmaf(tanh_f(e4.x + h4.x), v4.x, a0);
                a1 = fmaf(tanh_f(e4.y + h4.y), v4.y, a1);
                a2 = fmaf(tanh_f(e4.z + h4.z), v4.z, a2);
                a3 = fmaf(tanh_f(e4.w + h4.w), v4.w, a3);
            }
            sm.p1.tmp[kh][s] = (a0 + a1) + (a2 + a3);
            __syncthreads();

            float sc = 0.f;
            if (tid < 128) {
                sc = sm.p1.tmp[0][tid] + sm.p1.tmp[1][tid];
                sm.p1.red[tid] = sc;
            }
            __syncthreads();
            for (int off = 64; off >= 1; off >>= 1) {
                if (tid < off) sm.p1.red[tid] = fmaxf(sm.p1.red[tid], sm.p1.red[tid + off]);
                __syncthreads();
            }
            float mx = sm.p1.red[0];
            __syncthreads();
            if (tid < 128) {
                float e = __expf(sc - mx);
                sm.p1.att[tid] = e;
                sm.p1.red[tid] = e;
            }
            __syncthreads();
            if (tid < 64) sm.p1.red[tid] += sm.p1.red[tid + 64];
            __syncthreads();
            for (int off = 32; off >= 1; off >>= 1) {
                if (tid < off) sm.p1.red[tid] += sm.p1.red[tid + off];
                __syncthreads();
            }
            inv = 1.f / sm.p1.red[0];

            // ctx slice: d in [oct*128, +128), s split in halves across tid>>7
            int dd = tid & 127;
            int sh = tid >> 7;
            int d  = oct * 128 + dd;
            const float* ebase = ENC + (ab * S_ + sh * 64) * 1024 + d;
            float acc = 0.f;
#pragma unroll 4
            for (int s2 = 0; s2 < 64; ++s2)
                acc = fmaf(sm.p1.att[sh * 64 + s2], ebase[s2 * 1024], acc);
            __syncthreads();                 // att reads done before tmp overwrite
            sm.p1.tmp[sh][dd] = acc;
            __syncthreads();
            if (tid < 128)
                sysw_f(CTX + ab * 1024 + oct * 128 + tid,
                       (sm.p1.tmp[0][tid] + sm.p1.tmp[1][tid]) * inv);
        }
        flag_barrier(flags, wg, (unsigned)(3 * t + 2));

        // ================= P2: gates (din + ctx parts) + cell =================
        {
            // stage CTX + DIN into LDS
#pragma unroll
            for (int u = 0; u < 32; ++u) {
                int n = tid + u * 256;                 // 0..8191
                int b2 = n >> 10, d = n & 1023;
                sm.p2.ctx[b2][d] = sysr_f(CTX + n);
            }
#pragma unroll
            for (int u = 0; u < 4; ++u) {
                int n = tid + u * 256;                 // 0..1023
                int b2 = n >> 7, m = n & 127;
                sm.p2.din[b2][m] = sysr_f(DIN + n);
            }
            __syncthreads();

            float acc = hdec_acc;
            float a0 = 0.f, a1 = 0.f, a2 = 0.f, a3 = 0.f;
#pragma unroll
            for (int k = 0; k < 80; k += 4) {
                float4 wv = *(const float4*)(wih_row + k);
                float4 xv = *(const float4*)&sm.p2.din[bb][k];
                a0 = fmaf(wv.x, xv.x, a0); a1 = fmaf(wv.y, xv.y, a1);
                a2 = fmaf(wv.z, xv.z, a2); a3 = fmaf(wv.w, xv.w, a3);
            }
#pragma unroll 8
            for (int k = 0; k < 1024; k += 4) {
                float4 wv = *(const float4*)(wih_row + 80 + k);
                float4 xv = *(const float4*)&sm.p2.ctx[bb][k];
                a0 = fmaf(wv.x, xv.x, a0); a1 = fmaf(wv.y, xv.y, a1);
                a2 = fmaf(wv.z, xv.z, a2); a3 = fmaf(wv.w, xv.w, a3);
            }
            acc += (a0 + a1) + (a2 + a3);
            sm.p2.gsh[q][jj][bb] = acc;
            __syncthreads();
            if (q == 0) {
                float gi = sm.p2.gsh[0][jj][bb], gf = sm.p2.gsh[1][jj][bb];
                float gg = sm.p2.gsh[2][jj][bb], go = sm.p2.gsh[3][jj][bb];
                float c2 = sigm_f(gf) * c_reg + sigm_f(gi) * tanh_f(gg);
                float h2 = sigm_f(go) * tanh_f(c2);
                c_reg = c2;
                sysw_f(DH + bb * 512 + j, h2);
            }
        }
        flag_barrier(flags, wg, (unsigned)(3 * t + 3));
    }

    // ---- final mel (t = T-1) ----
    if (wg < 3) {
#pragma unroll
        for (int u = 0; u < 16; ++u) {
            int n = tid + u * 256;
            int b2 = n >> 9, k = n & 511;
            sm.p0.dh[b2][k] = sysr_f(DH + b2 * 512 + k);
        }
        __syncthreads();
        int id = wg * 256 + tid;
        if (id < 640) {
            int mr = id >> 3, b2 = id & 7;
            const float* wrow = mel_W + mr * 512;
            float a0 = 0.f, a1 = 0.f, a2 = 0.f, a3 = 0.f;
#pragma unroll 8
            for (int k = 0; k < 512; k += 4) {
                float4 wv = *(const float4*)(wrow + k);
                float4 hv = *(const float4*)&sm.p0.dh[b2][k];
                a0 = fmaf(wv.x, hv.x, a0); a1 = fmaf(wv.y, hv.y, a1);
                a2 = fmaf(wv.z, hv.z, a2); a3 = fmaf(wv.w, hv.w, a3);
            }
            out[b2 * MEL_ * T + mr * T + (T - 1)] = (a0 + a1) + (a2 + a3) + mel_b[mr];
        }
    }
}

// ---------------- host launch ----------------
extern "C" void kernel_launch(void* const* d_in, const int* in_sizes, int n_in,
                              void* d_out, int out_size, void* d_ws, size_t ws_size,
                              hipStream_t stream) {
    const int*   text  = (const int*)d_in[0];
    const float* emb   = (const float*)d_in[2];
    const float* Wih00 = (const float*)d_in[3];
    const float* Whh00 = (const float*)d_in[4];
    const float* bih00 = (const float*)d_in[5];
    const float* bhh00 = (const float*)d_in[6];
    const float* Wih01 = (const float*)d_in[7];
    const float* Whh01 = (const float*)d_in[8];
    const float* bih01 = (const float*)d_in[9];
    const float* bhh01 = (const float*)d_in[10];
    const float* Wih10 = (const float*)d_in[11];
    const float* Whh10 = (const float*)d_in[12];
    const float* bih10 = (const float*)d_in[13];
    const float* bhh10 = (const float*)d_in[14];
    const float* Wih11 = (const float*)d_in[15];
    const float* Whh11 = (const float*)d_in[16];
    const float* bih11 = (const float*)d_in[17];
    const float* bhh11 = (const float*)d_in[18];
    const float* attn_W = (const float*)d_in[19];
    const float* attn_b = (const float*)d_in[20];
    const float* attn_v = (const float*)d_in[21];
    const float* dec_Wih = (const float*)d_in[22];
    const float* dec_Whh = (const float*)d_in[23];
    const float* dec_bih = (const float*)d_in[24];
    const float* dec_bhh = (const float*)d_in[25];
    const float* mel_W = (const float*)d_in[26];
    const float* mel_b = (const float*)d_in[27];

    float* ws = (float*)d_ws;
    unsigned* flags = (unsigned*)d_ws;
    float* out = (float*)d_out;
    int T = out_size / (B_ * MEL_);   // 200

    // zero flags + recurrent state
    zero_kernel<<<ZERO_WORDS / 256, 256, 0, stream>>>(ws);

    // embedding
    embed_kernel<<<512, 256, 0, stream>>>(text, emb, ws + OFF_X0);

    // layer0 input projections (bias folded: bih + bhh)
    gemm_f32<<<dim3(32, 16), 256, 0, stream>>>(ws + OFF_X0, 512, Wih00, 512,
                                               bih00, bhh00, ws + OFF_GX0F, 2048, 512);
    gemm_f32<<<dim3(32, 16), 256, 0, stream>>>(ws + OFF_X0, 512, Wih01, 512,
                                               bih01, bhh01, ws + OFF_GX0B, 2048, 512);
    // layer0 recurrence
    lstm_kernel<<<128, 256, 0, stream>>>(ws + OFF_GX0F, ws + OFF_GX0B, Whh00, Whh01,
                                         ws + OFF_H0, ws + OFF_H0S, flags + FLG_L0);
    // layer1 input projections
    gemm_f32<<<dim3(32, 16), 256, 0, stream>>>(ws + OFF_H0, 1024, Wih10, 1024,
                                               bih10, bhh10, ws + OFF_GX1F, 2048, 1024);
    gemm_f32<<<dim3(32, 16), 256, 0, stream>>>(ws + OFF_H0, 1024, Wih11, 1024,
                                               bih11, bhh11, ws + OFF_GX1B, 2048, 1024);
    // layer1 recurrence -> enc
    lstm_kernel<<<128, 256, 0, stream>>>(ws + OFF_GX1F, ws + OFF_GX1B, Whh10, Whh11,
                                         ws + OFF_ENC, ws + OFF_H1S, flags + FLG_L1);
    // enc_part = enc @ W_e^T + attn_b   (W_e = attn_W[:, 512:], row stride 1536)
    gemm_f32<<<dim3(8, 16), 256, 0, stream>>>(ws + OFF_ENC, 1024, attn_W + 512, 1536,
                                              attn_b, nullptr, ws + OFF_ENCP, 512, 1024);
    // decoder (3 grid barriers / step)
    decoder_kernel<<<64, 256, 0, stream>>>(ws, attn_W, attn_v, dec_Wih, dec_Whh,
                                           dec_bih, dec_bhh, mel_W, mel_b, out, T,
                                           flags + FLG_DEC);
}

// Round 4
// 16692.381 us; speedup vs baseline: 1.6013x; 1.0287x over previous
//
#include <hip/hip_runtime.h>

// ---------------- problem constants ----------------
#define B_ 8
#define S_ 128
#define H_ 512
#define G_ 2048   // 4H
#define MEL_ 80

// ---------------- ws layout (32-bit word offsets) ----------------
// flag groups: each flag gets its own 64B line (16-word stride)
#define FLG_DEC    0        // 80 flags (1280 words, reserve 2048)
#define FLG_L0     2048     // lstm0: dir0 @ +0, dir1 @ +1024
#define FLG_L1     4096     // lstm1: dir0 @ +0, dir1 @ +1024
#define OFF_H0S    8192                 // lstm0 h [dir][pingpong][b][512] = 16384
#define OFF_H1S    (OFF_H0S + 16384)    // 16384
#define OFF_DH     (OFF_H1S + 16384)    // dec h [b][512] = 4096
#define OFF_DIN    (OFF_DH + 4096)      // din [b][128] = 1024 (80 used/row)
#define OFF_HW     (OFF_DIN + 1024)     // [b][512] = 4096
#define OFF_CTX    (OFF_HW + 4096)      // [b][1024] = 8192
#define ZERO_WORDS (OFF_CTX + 8192)     // = 58368 = 228*256
#define OFF_X0     58368                        // [bs][512]   524288
#define OFF_GX0F   (OFF_X0 + 524288)            // [bs][2048] 2097152
#define OFF_GX0B   (OFF_GX0F + 2097152)
#define OFF_H0     (OFF_GX0B + 2097152)         // [bs][1024] 1048576
#define OFF_GX1F   (OFF_H0 + 1048576)
#define OFF_GX1B   (OFF_GX1F + 2097152)
#define OFF_ENC    (OFF_GX1B + 2097152)         // [bs][1024] 1048576
#define OFF_ENCP   (OFF_ENC + 1048576)          // [bs][512]   524288

// ---------------- helpers ----------------
__device__ __forceinline__ float sigm_f(float x) {
    x = fminf(fmaxf(x, -30.f), 30.f);
    return 1.f / (1.f + __expf(-x));
}
__device__ __forceinline__ float tanh_f(float x) {
    x = fminf(fmaxf(x, -15.f), 15.f);
    float e = __expf(2.f * x);
    return (e - 1.f) / (e + 1.f);
}

// system-scope (LLC-coherent, cache-bypassing) scalar access for cross-WG state
__device__ __forceinline__ void sysw_u(unsigned* p, unsigned v) {
    __hip_atomic_store(p, v, __ATOMIC_RELAXED, __HIP_MEMORY_SCOPE_SYSTEM);
}
__device__ __forceinline__ unsigned sysr_u(const unsigned* p) {
    return __hip_atomic_load(p, __ATOMIC_RELAXED, __HIP_MEMORY_SCOPE_SYSTEM);
}
__device__ __forceinline__ void sysw_f(float* p, float v) {
    sysw_u((unsigned*)p, __float_as_uint(v));
}
__device__ __forceinline__ float sysr_f(const float* p) {
    return __uint_as_float(sysr_u((const unsigned*)p));
}

// flag-array grid barrier for an nwg-WG group (nwg <= 256).
__device__ __forceinline__ void flag_barrier(unsigned* flags, int wg, unsigned phase, int nwg) {
    asm volatile("s_waitcnt vmcnt(0) lgkmcnt(0)" ::: "memory");
    __syncthreads();
    if (threadIdx.x == 0)
        sysw_u(flags + wg * 16, phase);
    if (threadIdx.x < (unsigned)nwg) {
        while (sysr_u(flags + threadIdx.x * 16) < phase)
            __builtin_amdgcn_s_sleep(2);
    }
    asm volatile("s_waitcnt vmcnt(0)" ::: "memory");
    __syncthreads();
}

// ---------------- zero init ----------------
__global__ __launch_bounds__(256) void zero_kernel(float* p) {
    p[blockIdx.x * 256 + threadIdx.x] = 0.f;
}

// ---------------- embedding ----------------
__global__ __launch_bounds__(256) void embed_kernel(const int* __restrict__ text,
                                                    const float* __restrict__ emb,
                                                    float* __restrict__ X) {
    int i = blockIdx.x * 256 + threadIdx.x;   // float4 id, 131072 total
    int bs = i >> 7;
    int h4 = i & 127;
    int ch = text[bs];
    ((float4*)X)[i] = ((const float4*)emb)[ch * 128 + h4];
}

// ---------------- f32 GEMM: C[M,N] = A[M,K] * W[N,K]^T + b1 (+ b2) ----------------
__global__ __launch_bounds__(256) void gemm_f32(const float* __restrict__ A, int lda,
                                                const float* __restrict__ W, int ldw,
                                                const float* __restrict__ b1,
                                                const float* __restrict__ b2,
                                                float* __restrict__ C, int ldc, int K) {
    __shared__ float As[32][68];
    __shared__ float Ws[32][68];
    int tid = threadIdx.x;
    int tx = tid & 15, ty = tid >> 4;
    int n0 = blockIdx.x * 64, m0 = blockIdx.y * 64;
    float acc[4][4] = {};
    int r  = tid >> 3;
    int c4 = (tid & 7) * 4;
    for (int k0 = 0; k0 < K; k0 += 32) {
        float4 a0 = *(const float4*)&A[(m0 + r) * lda + k0 + c4];
        float4 a1 = *(const float4*)&A[(m0 + r + 32) * lda + k0 + c4];
        float4 w0 = *(const float4*)&W[(n0 + r) * ldw + k0 + c4];
        float4 w1 = *(const float4*)&W[(n0 + r + 32) * ldw + k0 + c4];
        As[c4 + 0][r] = a0.x; As[c4 + 1][r] = a0.y; As[c4 + 2][r] = a0.z; As[c4 + 3][r] = a0.w;
        As[c4 + 0][r + 32] = a1.x; As[c4 + 1][r + 32] = a1.y; As[c4 + 2][r + 32] = a1.z; As[c4 + 3][r + 32] = a1.w;
        Ws[c4 + 0][r] = w0.x; Ws[c4 + 1][r] = w0.y; Ws[c4 + 2][r] = w0.z; Ws[c4 + 3][r] = w0.w;
        Ws[c4 + 0][r + 32] = w1.x; Ws[c4 + 1][r + 32] = w1.y; Ws[c4 + 2][r + 32] = w1.z; Ws[c4 + 3][r + 32] = w1.w;
        __syncthreads();
#pragma unroll 8
        for (int kk = 0; kk < 32; ++kk) {
            float4 av = *(const float4*)&As[kk][ty * 4];
            float4 wv = *(const float4*)&Ws[kk][tx * 4];
            acc[0][0] = fmaf(av.x, wv.x, acc[0][0]); acc[0][1] = fmaf(av.x, wv.y, acc[0][1]);
            acc[0][2] = fmaf(av.x, wv.z, acc[0][2]); acc[0][3] = fmaf(av.x, wv.w, acc[0][3]);
            acc[1][0] = fmaf(av.y, wv.x, acc[1][0]); acc[1][1] = fmaf(av.y, wv.y, acc[1][1]);
            acc[1][2] = fmaf(av.y, wv.z, acc[1][2]); acc[1][3] = fmaf(av.y, wv.w, acc[1][3]);
            acc[2][0] = fmaf(av.z, wv.x, acc[2][0]); acc[2][1] = fmaf(av.z, wv.y, acc[2][1]);
            acc[2][2] = fmaf(av.z, wv.z, acc[2][2]); acc[2][3] = fmaf(av.z, wv.w, acc[2][3]);
            acc[3][0] = fmaf(av.w, wv.x, acc[3][0]); acc[3][1] = fmaf(av.w, wv.y, acc[3][1]);
            acc[3][2] = fmaf(av.w, wv.z, acc[3][2]); acc[3][3] = fmaf(av.w, wv.w, acc[3][3]);
        }
        __syncthreads();
    }
#pragma unroll
    for (int i = 0; i < 4; ++i)
#pragma unroll
        for (int j = 0; j < 4; ++j) {
            int n = n0 + tx * 4 + j;
            int m = m0 + ty * 4 + i;
            float bias = b1[n] + (b2 ? b2[n] : 0.f);
            C[m * ldc + n] = acc[i][j] + bias;
        }
}

// ---------------- persistent bidirectional LSTM layer ----------------
// grid 128 WGs: dir = wg>>6 (independent 64-WG barrier groups), slot = wg&63
__global__ __launch_bounds__(256) void lstm_kernel(const float* __restrict__ GXf,
                                                   const float* __restrict__ GXb,
                                                   const float* __restrict__ Whh_f,
                                                   const float* __restrict__ Whh_b,
                                                   float* __restrict__ Hout,
                                                   float* __restrict__ hstate,
                                                   unsigned* __restrict__ flagsL) {
    int wg = blockIdx.x;
    int dir = wg >> 6;
    int slot = wg & 63;
    const float* GX  = dir ? GXb : GXf;
    const float* Whh = dir ? Whh_b : Whh_f;
    float* hs0 = hstate + dir * 8192;   // [pingpong][b][512]
    unsigned* flags = flagsL + dir * 1024;

    int tid = threadIdx.x;
    int q  = tid >> 6;
    int jj = (tid >> 3) & 7;
    int bb = tid & 7;
    int j   = slot * 8 + jj;
    int row = q * 512 + j;
    const float* wr = Whh + row * 512;

    __shared__ float hsh[8][516];
    __shared__ float gsh[4][8][8];

    float c_reg = 0.f;   // cell state lives in registers of the q==0 threads

    for (int t = 0; t < 128; ++t) {
        int st = dir ? (127 - t) : t;
        const float* hsr = hs0 + (t & 1) * 4096;
        float* hsw = hs0 + ((t & 1) ^ 1) * 4096;
        // stage h into LDS (system loads: h written by other WGs at LLC)
#pragma unroll
        for (int u = 0; u < 16; ++u) {
            int n = tid + u * 256;           // 0..4095
            int b2 = n >> 9, k = n & 511;
            hsh[b2][k] = sysr_f(hsr + b2 * 512 + k);
        }
        __syncthreads();

        float acc = GX[(bb * S_ + st) * G_ + row];
        float a0 = 0.f, a1 = 0.f, a2 = 0.f, a3 = 0.f;
#pragma unroll 8
        for (int k = 0; k < 512; k += 4) {
            float4 wv = *(const float4*)(wr + k);
            float4 hv = *(const float4*)&hsh[bb][k];
            a0 = fmaf(wv.x, hv.x, a0);
            a1 = fmaf(wv.y, hv.y, a1);
            a2 = fmaf(wv.z, hv.z, a2);
            a3 = fmaf(wv.w, hv.w, a3);
        }
        acc += (a0 + a1) + (a2 + a3);
        gsh[q][jj][bb] = acc;
        __syncthreads();

        if (q == 0) {
            float gi = gsh[0][jj][bb], gf = gsh[1][jj][bb];
            float gg = gsh[2][jj][bb], go = gsh[3][jj][bb];
            float c2 = sigm_f(gf) * c_reg + sigm_f(gi) * tanh_f(gg);
            float h2 = sigm_f(go) * tanh_f(c2);
            c_reg = c2;
            sysw_f(hsw + bb * 512 + j, h2);
            Hout[(bb * S_ + st) * 1024 + dir * 512 + j] = h2;
        }
        flag_barrier(flags, slot, (unsigned)(t + 1), 64);
    }
}

// ---------------- persistent attention decoder ----------------
// 80 WGs: 0..63 gate-WGs (own 8 gate-cols x 4 gates, all batches — weight slices
// L2-local per XCD); 64..79 attention-WGs, 2 per batch (u&7 = batch -> XCD-local
// ENC/ENCP under round-robin dispatch; u>>3 = d-half for ctx).
// 3 barriers/step: P0 {stage DH; hdec->reg; hW distributed; mel} | P1 {attn} |
// P2 {gates+cell}.
union DecSMem {
    struct { float dh[8][516]; float gshW[4][8][8]; float gshM[4][8][8]; } p0;
    struct { float hw[516]; float tmp[2][128]; float att[128]; float red[128]; } p1;
    struct { float ctx[8][1028]; float din[8][132]; float gsh[4][8][8]; } p2;
};

__global__ __launch_bounds__(256) void decoder_kernel(float* __restrict__ ws,
                                                      const float* __restrict__ attn_W,
                                                      const float* __restrict__ attn_v,
                                                      const float* __restrict__ dec_Wih,
                                                      const float* __restrict__ dec_Whh,
                                                      const float* __restrict__ dec_bih,
                                                      const float* __restrict__ dec_bhh,
                                                      const float* __restrict__ mel_W,
                                                      const float* __restrict__ mel_b,
                                                      float* __restrict__ out, int T,
                                                      unsigned* __restrict__ flags) {
    float* ENC  = ws + OFF_ENC;
    float* ENCP = ws + OFF_ENCP;
    float* DH   = ws + OFF_DH;
    float* DIN  = ws + OFF_DIN;
    float* HW   = ws + OFF_HW;
    float* CTX  = ws + OFF_CTX;

    int wg = blockIdx.x;     // 0..79
    int tid = threadIdx.x;

    __shared__ DecSMem sm;

    // gate-WG mapping
    int q  = tid >> 6;
    int jj = (tid >> 3) & 7;
    int bb = tid & 7;
    int j   = wg * 8 + jj;          // valid for wg<64
    int row = q * 512 + j;
    const float* whh_row = dec_Whh + (wg < 64 ? row * 512 : 0);
    const float* wih_row = dec_Wih + (wg < 64 ? row * 1104 : 0);
    float bias_row = (wg < 64) ? (dec_bih[row] + dec_bhh[row]) : 0.f;
    // distributed hW: gate WG wg owns attn_W row hr = wg*8+jj, k-quarter q
    const float* wh_part = attn_W + (wg < 64 ? ((wg * 8 + jj) * 1536 + q * 128) : 0);
    // distributed mel (WGs 0..9): row mr = wg*8+jj, k-quarter q
    const float* mel_part = mel_W + (wg < 10 ? ((wg * 8 + jj) * 512 + q * 128) : 0);

    // attention-WG mapping
    int au   = wg - 64;
    int ab   = au & 7;        // batch (== XCD id under round-robin)
    int ah   = au >> 3;       // d-half: [ah*512, +512)

    float c_reg = 0.f;        // decoder cell state (gate WGs, q==0 threads)
    float hdec_acc = 0.f;

    for (int t = 0; t < T; ++t) {
        // ================= P0 (gate WGs): stage DH; hdec; hW; mel =================
        if (wg < 64) {
#pragma unroll
            for (int u = 0; u < 16; ++u) {
                int n = tid + u * 256;
                int b2 = n >> 9, k = n & 511;
                sm.p0.dh[b2][k] = sysr_f(DH + b2 * 512 + k);
            }
            __syncthreads();

            // hdec: each thread one (row, bb) dot, kept in register across phases
            {
                float a0 = bias_row, a1 = 0.f, a2 = 0.f, a3 = 0.f;
#pragma unroll 8
                for (int k = 0; k < 512; k += 4) {
                    float4 wv = *(const float4*)(whh_row + k);
                    float4 hv = *(const float4*)&sm.p0.dh[bb][k];
                    a0 = fmaf(wv.x, hv.x, a0); a1 = fmaf(wv.y, hv.y, a1);
                    a2 = fmaf(wv.z, hv.z, a2); a3 = fmaf(wv.w, hv.w, a3);
                }
                hdec_acc = (a0 + a1) + (a2 + a3);
            }
            // hW partial: row wg*8+jj, batch bb, k in [q*128, +128)
            {
                float a0 = 0.f, a1 = 0.f, a2 = 0.f, a3 = 0.f;
                const float* hp = &sm.p0.dh[bb][q * 128];
#pragma unroll 8
                for (int k = 0; k < 128; k += 4) {
                    float4 wv = *(const float4*)(wh_part + k);
                    float4 hv = *(const float4*)(hp + k);
                    a0 = fmaf(wv.x, hv.x, a0); a1 = fmaf(wv.y, hv.y, a1);
                    a2 = fmaf(wv.z, hv.z, a2); a3 = fmaf(wv.w, hv.w, a3);
                }
                sm.p0.gshW[q][jj][bb] = (a0 + a1) + (a2 + a3);
            }
            // mel partial (WGs 0..9 cover rows 0..79), from h_{t-1}
            if (wg < 10) {
                float a0 = 0.f, a1 = 0.f, a2 = 0.f, a3 = 0.f;
                const float* hp = &sm.p0.dh[bb][q * 128];
#pragma unroll 8
                for (int k = 0; k < 128; k += 4) {
                    float4 wv = *(const float4*)(mel_part + k);
                    float4 hv = *(const float4*)(hp + k);
                    a0 = fmaf(wv.x, hv.x, a0); a1 = fmaf(wv.y, hv.y, a1);
                    a2 = fmaf(wv.z, hv.z, a2); a3 = fmaf(wv.w, hv.w, a3);
                }
                sm.p0.gshM[q][jj][bb] = (a0 + a1) + (a2 + a3);
            }
            __syncthreads();
            if (q == 0) {
                int hr = wg * 8 + jj;
                sysw_f(HW + bb * 512 + hr,
                       sm.p0.gshW[0][jj][bb] + sm.p0.gshW[1][jj][bb] +
                       sm.p0.gshW[2][jj][bb] + sm.p0.gshW[3][jj][bb]);
                if (wg < 10 && t > 0) {
                    int mr = wg * 8 + jj;
                    float mel = sm.p0.gshM[0][jj][bb] + sm.p0.gshM[1][jj][bb] +
                                sm.p0.gshM[2][jj][bb] + sm.p0.gshM[3][jj][bb] + mel_b[mr];
                    sysw_f(DIN + bb * 128 + mr, mel);
                    out[bb * MEL_ * T + mr * T + (t - 1)] = mel;
                }
            }
        }
        flag_barrier(flags, wg, (unsigned)(3 * t + 1), 80);

        // ================= P1 (attn WGs): scores + softmax + ctx half =================
        if (wg >= 64) {
            for (int n = tid; n < 512; n += 256)
                sm.p1.hw[n] = sysr_f(HW + ab * 512 + n);
            __syncthreads();

            // scores: s = tid&127, k-half = tid>>7 (ENCP reads are XCD-L2-resident)
            int s  = tid & 127;
            int kh = tid >> 7;
            const float* ep = ENCP + (ab * S_ + s) * 512 + kh * 256;
            const float* hw = sm.p1.hw + kh * 256;
            const float* vv = attn_v + kh * 256;
            float a0 = 0.f, a1 = 0.f, a2 = 0.f, a3 = 0.f;
#pragma unroll 4
            for (int k = 0; k < 256; k += 4) {
                float4 e4 = *(const float4*)(ep + k);
                float4 h4 = *(const float4*)(hw + k);
                float4 v4 = *(const float4*)(vv + k);
                a0 = fmaf(tanh_f(e4.x + h4.x), v4.x, a0);
                a1 = fmaf(tanh_f(e4.y + h4.y), v4.y, a1);
                a2 = fmaf(tanh_f(e4.z + h4.z), v4.z, a2);
                a3 = fmaf(tanh_f(e4.w + h4.w), v4.w, a3);
            }
            sm.p1.tmp[kh][s] = (a0 + a1) + (a2 + a3);
            __syncthreads();

            float sc = 0.f;
            if (tid < 128) {
                sc = sm.p1.tmp[0][tid] + sm.p1.tmp[1][tid];
                sm.p1.red[tid] = sc;
            }
            __syncthreads();
            for (int off = 64; off >= 1; off >>= 1) {
                if (tid < off) sm.p1.red[tid] = fmaxf(sm.p1.red[tid], sm.p1.red[tid + off]);
                __syncthreads();
            }
            float mx = sm.p1.red[0];
            __syncthreads();
            if (tid < 128) {
                float e = __expf(sc - mx);
                sm.p1.att[tid] = e;
                sm.p1.red[tid] = e;
            }
            __syncthreads();
            if (tid < 64) sm.p1.red[tid] += sm.p1.red[tid + 64];
            __syncthreads();
            for (int off = 32; off >= 1; off >>= 1) {
                if (tid < off) sm.p1.red[tid] += sm.p1.red[tid + off];
                __syncthreads();
            }
            float inv = 1.f / sm.p1.red[0];

            // ctx: d-half [ah*512, +512), 2 dims/thread (ENC reads XCD-L2-resident)
            int d = ah * 512 + tid * 2;
            const float* ebase = ENC + ab * S_ * 1024 + d;
            float acc0 = 0.f, acc1 = 0.f;
#pragma unroll 4
            for (int s2 = 0; s2 < 128; ++s2) {
                float a = sm.p1.att[s2];
                float2 ev = *(const float2*)(ebase + s2 * 1024);
                acc0 = fmaf(a, ev.x, acc0);
                acc1 = fmaf(a, ev.y, acc1);
            }
            sysw_f(CTX + ab * 1024 + d,     acc0 * inv);
            sysw_f(CTX + ab * 1024 + d + 1, acc1 * inv);
        }
        flag_barrier(flags, wg, (unsigned)(3 * t + 2), 80);

        // ================= P2 (gate WGs): gates (din + ctx) + cell =================
        if (wg < 64) {
#pragma unroll
            for (int u = 0; u < 32; ++u) {
                int n = tid + u * 256;                 // 0..8191
                int b2 = n >> 10, d = n & 1023;
                sm.p2.ctx[b2][d] = sysr_f(CTX + n);
            }
#pragma unroll
            for (int u = 0; u < 4; ++u) {
                int n = tid + u * 256;                 // 0..1023
                int b2 = n >> 7, m = n & 127;
                sm.p2.din[b2][m] = sysr_f(DIN + n);
            }
            __syncthreads();

            float acc = hdec_acc;
            float a0 = 0.f, a1 = 0.f, a2 = 0.f, a3 = 0.f;
#pragma unroll
            for (int k = 0; k < 80; k += 4) {
                float4 wv = *(const float4*)(wih_row + k);
                float4 xv = *(const float4*)&sm.p2.din[bb][k];
                a0 = fmaf(wv.x, xv.x, a0); a1 = fmaf(wv.y, xv.y, a1);
                a2 = fmaf(wv.z, xv.z, a2); a3 = fmaf(wv.w, xv.w, a3);
            }
#pragma unroll 8
            for (int k = 0; k < 1024; k += 4) {
                float4 wv = *(const float4*)(wih_row + 80 + k);
                float4 xv = *(const float4*)&sm.p2.ctx[bb][k];
                a0 = fmaf(wv.x, xv.x, a0); a1 = fmaf(wv.y, xv.y, a1);
                a2 = fmaf(wv.z, xv.z, a2); a3 = fmaf(wv.w, xv.w, a3);
            }
            acc += (a0 + a1) + (a2 + a3);
            sm.p2.gsh[q][jj][bb] = acc;
            __syncthreads();
            if (q == 0) {
                float gi = sm.p2.gsh[0][jj][bb], gf = sm.p2.gsh[1][jj][bb];
                float gg = sm.p2.gsh[2][jj][bb], go = sm.p2.gsh[3][jj][bb];
                float c2 = sigm_f(gf) * c_reg + sigm_f(gi) * tanh_f(gg);
                float h2 = sigm_f(go) * tanh_f(c2);
                c_reg = c2;
                sysw_f(DH + bb * 512 + j, h2);
            }
        }
        flag_barrier(flags, wg, (unsigned)(3 * t + 3), 80);
    }

    // ---- final mel (t = T-1): WGs 0..9, re-stage final DH ----
    if (wg < 10) {
#pragma unroll
        for (int u = 0; u < 16; ++u) {
            int n = tid + u * 256;
            int b2 = n >> 9, k = n & 511;
            sm.p0.dh[b2][k] = sysr_f(DH + b2 * 512 + k);
        }
        __syncthreads();
        float a0 = 0.f, a1 = 0.f, a2 = 0.f, a3 = 0.f;
        const float* hp = &sm.p0.dh[bb][q * 128];
#pragma unroll 8
        for (int k = 0; k < 128; k += 4) {
            float4 wv = *(const float4*)(mel_part + k);
            float4 hv = *(const float4*)(hp + k);
            a0 = fmaf(wv.x, hv.x, a0); a1 = fmaf(wv.y, hv.y, a1);
            a2 = fmaf(wv.z, hv.z, a2); a3 = fmaf(wv.w, hv.w, a3);
        }
        sm.p0.gshM[q][jj][bb] = (a0 + a1) + (a2 + a3);
        __syncthreads();
        if (q == 0) {
            int mr = wg * 8 + jj;
            float mel = sm.p0.gshM[0][jj][bb] + sm.p0.gshM[1][jj][bb] +
                        sm.p0.gshM[2][jj][bb] + sm.p0.gshM[3][jj][bb] + mel_b[mr];
            out[bb * MEL_ * T + mr * T + (T - 1)] = mel;
        }
    }
}

// ---------------- host launch ----------------
extern "C" void kernel_launch(void* const* d_in, const int* in_sizes, int n_in,
                              void* d_out, int out_size, void* d_ws, size_t ws_size,
                              hipStream_t stream) {
    const int*   text  = (const int*)d_in[0];
    const float* emb   = (const float*)d_in[2];
    const float* Wih00 = (const float*)d_in[3];
    const float* Whh00 = (const float*)d_in[4];
    const float* bih00 = (const float*)d_in[5];
    const float* bhh00 = (const float*)d_in[6];
    const float* Wih01 = (const float*)d_in[7];
    const float* Whh01 = (const float*)d_in[8];
    const float* bih01 = (const float*)d_in[9];
    const float* bhh01 = (const float*)d_in[10];
    const float* Wih10 = (const float*)d_in[11];
    const float* Whh10 = (const float*)d_in[12];
    const float* bih10 = (const float*)d_in[13];
    const float* bhh10 = (const float*)d_in[14];
    const float* Wih11 = (const float*)d_in[15];
    const float* Whh11 = (const float*)d_in[16];
    const float* bih11 = (const float*)d_in[17];
    const float* bhh11 = (const float*)d_in[18];
    const float* attn_W = (const float*)d_in[19];
    const float* attn_b = (const float*)d_in[20];
    const float* attn_v = (const float*)d_in[21];
    const float* dec_Wih = (const float*)d_in[22];
    const float* dec_Whh = (const float*)d_in[23];
    const float* dec_bih = (const float*)d_in[24];
    const float* dec_bhh = (const float*)d_in[25];
    const float* mel_W = (const float*)d_in[26];
    const float* mel_b = (const float*)d_in[27];

    float* ws = (float*)d_ws;
    unsigned* flags = (unsigned*)d_ws;
    float* out = (float*)d_out;
    int T = out_size / (B_ * MEL_);   // 200

    // zero flags + recurrent state
    zero_kernel<<<ZERO_WORDS / 256, 256, 0, stream>>>(ws);

    // embedding
    embed_kernel<<<512, 256, 0, stream>>>(text, emb, ws + OFF_X0);

    // layer0 input projections (bias folded: bih + bhh)
    gemm_f32<<<dim3(32, 16), 256, 0, stream>>>(ws + OFF_X0, 512, Wih00, 512,
                                               bih00, bhh00, ws + OFF_GX0F, 2048, 512);
    gemm_f32<<<dim3(32, 16), 256, 0, stream>>>(ws + OFF_X0, 512, Wih01, 512,
                                               bih01, bhh01, ws + OFF_GX0B, 2048, 512);
    // layer0 recurrence
    lstm_kernel<<<128, 256, 0, stream>>>(ws + OFF_GX0F, ws + OFF_GX0B, Whh00, Whh01,
                                         ws + OFF_H0, ws + OFF_H0S, flags + FLG_L0);
    // layer1 input projections
    gemm_f32<<<dim3(32, 16), 256, 0, stream>>>(ws + OFF_H0, 1024, Wih10, 1024,
                                               bih10, bhh10, ws + OFF_GX1F, 2048, 1024);
    gemm_f32<<<dim3(32, 16), 256, 0, stream>>>(ws + OFF_H0, 1024, Wih11, 1024,
                                               bih11, bhh11, ws + OFF_GX1B, 2048, 1024);
    // layer1 recurrence -> enc
    lstm_kernel<<<128, 256, 0, stream>>>(ws + OFF_GX1F, ws + OFF_GX1B, Whh10, Whh11,
                                         ws + OFF_ENC, ws + OFF_H1S, flags + FLG_L1);
    // enc_part = enc @ W_e^T + attn_b   (W_e = attn_W[:, 512:], row stride 1536)
    gemm_f32<<<dim3(8, 16), 256, 0, stream>>>(ws + OFF_ENC, 1024, attn_W + 512, 1536,
                                              attn_b, nullptr, ws + OFF_ENCP, 512, 1024);
    // decoder: 64 gate WGs + 16 attention WGs, 3 grid barriers / step
    decoder_kernel<<<80, 256, 0, stream>>>(ws, attn_W, attn_v, dec_Wih, dec_Whh,
                                           dec_bih, dec_bhh, mel_W, mel_b, out, T,
                                           flags + FLG_DEC);
}